// Round 8
// baseline (380.115 us; speedup 1.0000x reference)
//
#include <hip/hip_runtime.h>
#include <hip/hip_bf16.h>
#include <cstdint>

typedef __attribute__((ext_vector_type(8))) short bf16x8;   // 8 bf16 (4 VGPRs)
typedef __attribute__((ext_vector_type(4))) short bf16x4;   // 4 bf16 (2 VGPRs)
typedef __attribute__((ext_vector_type(4))) float f32x4;    // MFMA C/D

#define BN_EPS 1e-5f

// ---------------------------------------------------------------------------
// prep1: fold BN1 + ring telescoping into V (box-feature weights), b1eff.
// ---------------------------------------------------------------------------
__global__ __launch_bounds__(256) void prep1_kernel(
    const float* __restrict__ W1, const float* __restrict__ cb1,
    const float* __restrict__ g1, const float* __restrict__ be1,
    const float* __restrict__ mu1, const float* __restrict__ va1,
    __hip_bfloat16* __restrict__ V, float* __restrict__ b1e)
{
  int o = blockIdx.x;
  int t = threadIdx.x;
  const float* wrow = W1 + (size_t)o * 1248;
  float acc = 0.f;
  for (int i = t; i < 1248; i += 256) {
    float s = g1[i] * rsqrtf(va1[i] + BN_EPS);
    float w = wrow[i];
    acc += w * (be1[i] - mu1[i] * s);
    float g = w * s;
    float gn = 0.f;
    if (i < 1152) {  // has a next-ring partner
      float sn = g1[i + 96] * rsqrtf(va1[i + 96] + BN_EPS);
      gn = wrow[i + 96] * sn;
    }
    V[(size_t)o * 1248 + i] = __float2bfloat16(g - gn);
  }
  for (int d = 32; d > 0; d >>= 1) acc += __shfl_down(acc, d);
  __shared__ float red[4];
  int lane = t & 63, wv = t >> 6;
  if (lane == 0) red[wv] = acc;
  __syncthreads();
  if (t == 0) b1e[o] = cb1[o] + red[0] + red[1] + red[2] + red[3];
}

// ---------------------------------------------------------------------------
// prep2: fold BN2 into W2eff, b2eff.
// ---------------------------------------------------------------------------
__global__ __launch_bounds__(256) void prep2_kernel(
    const float* __restrict__ W2, const float* __restrict__ cb2,
    const float* __restrict__ g2, const float* __restrict__ be2,
    const float* __restrict__ mu2, const float* __restrict__ va2,
    __hip_bfloat16* __restrict__ W2e, float* __restrict__ b2e)
{
  int o = blockIdx.x;
  int t = threadIdx.x;
  const float* wrow = W2 + (size_t)o * 512;
  float acc = 0.f;
  for (int j = t; j < 512; j += 256) {
    float s = g2[j] * rsqrtf(va2[j] + BN_EPS);
    float wv = wrow[j];
    acc += wv * (be2[j] - mu2[j] * s);
    W2e[(size_t)o * 512 + j] = __float2bfloat16(wv * s);
  }
  for (int d = 32; d > 0; d >>= 1) acc += __shfl_down(acc, d);
  __shared__ float red[4];
  int lane = t & 63, wv2 = t >> 6;
  if (lane == 0) red[wv2] = acc;
  __syncthreads();
  if (t == 0) b2e[o] = cb2[o] + red[0] + red[1] + red[2] + red[3];
}

// ---------------------------------------------------------------------------
// sat v2: one block per (b,c) plane. Exclusive SAT [129][132].
// ---------------------------------------------------------------------------
__global__ __launch_bounds__(128) void sat_kernel(
    const float* __restrict__ x, float* __restrict__ SAT)
{
  int plane = blockIdx.x;
  const float* xp = x + (size_t)plane * 16384;
  __shared__ float tile[16384];   // [r][granule-swizzled]
  int t = threadIdx.x;
  for (int i4 = t; i4 < 4096; i4 += 128) {
    int r = i4 >> 5;
    int g = i4 & 31;                       // granule of 4 floats
    float4 v = *(const float4*)(xp + (size_t)r * 128 + g * 4);
    *(float4*)(tile + r * 128 + ((g ^ (r & 31)) << 2)) = v;
  }
  __syncthreads();
  {  // row scan: thread = row, float4 granules with carry
    int r = t;
    float carry = 0.f;
    for (int g = 0; g < 32; ++g) {
      float* p = tile + r * 128 + ((g ^ (r & 31)) << 2);
      float4 v = *(float4*)p;
      float s0 = carry + v.x, s1 = s0 + v.y, s2 = s1 + v.z, s3 = s2 + v.w;
      float4 o; o.x = s0; o.y = s1; o.z = s2; o.w = s3;
      *(float4*)p = o;
      carry = s3;
    }
  }
  __syncthreads();
  float* Sg = SAT + (size_t)plane * 17028;  // 129*132
  Sg[t] = 0.f;                   // row 0, cols 0..127
  if (t < 4) Sg[128 + t] = 0.f;  // row 0, cols 128..131
  Sg[(t + 1) * 132] = 0.f;       // col 0, rows 1..128
  int gc = t >> 2, wc = t & 3;
  float run = 0.f;
  for (int r = 0; r < 128; ++r) {
    run += tile[r * 128 + ((gc ^ (r & 31)) << 2) + wc];
    Sg[(r + 1) * 132 + t + 1] = run;
  }
}

// ---------------------------------------------------------------------------
// fused v5: feat + gemm1 + gemm2, ring-granular 2-deep software pipeline.
// One block per image row, 1024 thr / 16 waves, wave tile M64xN64.
// E and As double-buffered (LDS 154.6KB, 1 block/CU); per ring j ONE barrier:
//   issue efill(j+2) loads -> MFMA ring j (frags prefetched) ->
//   build As[j+1] from E[j+1] -> commit E[j+2] -> barrier.
// Rotation: E[j&1] is dead when efill(j+2) overwrites it; As[(j+1)&1]
// written while As[j&1] is MFMA'd. Epilogue (reuses LDS as Yst[128][520]):
// bias+relu Y1 tile, then out = W2e x Y1^T in-block (as v4).
// ---------------------------------------------------------------------------
__global__ __launch_bounds__(1024) void fused1_kernel(
    const float* __restrict__ SAT, const __hip_bfloat16* __restrict__ V,
    const float* __restrict__ b1e, const __hip_bfloat16* __restrict__ W2e,
    const float* __restrict__ b2e, float* __restrict__ out, int nb, int b0)
{
  extern __shared__ __align__(16) char smem[];
  const int EN = 96 * 132;                   // E buffer floats
  const int AN = 128 * 104;                  // As buffer bf16
  float* E0 = (float*)smem;                  // [2][96][132] fp32 = 101376 B
  __hip_bfloat16* A0 = (__hip_bfloat16*)(smem + 2 * EN * 4);  // [2][128][104]

  int blk = blockIdx.x;
  int rows_per_xcd = (nb * 128) >> 3;
  int r = (blk & 7) * rows_per_xcd + (blk >> 3);
  int bL = r >> 7, y = r & 127;

  int t = threadIdx.x;
  int lane = t & 63, wv = t >> 6;            // 16 waves
  int wm = wv & 1, wn = wv >> 1;             // M-half (64), N-slab (64)
  int lr = lane & 15, quad = lane >> 4;
  int pxb = t & 127;                         // build/efill pixel id

  const float* Sb = SAT + (size_t)bL * 96 * 17028;

  f32x4 acc[4][4];
#pragma unroll
  for (int i = 0; i < 4; ++i)
#pragma unroll
    for (int jn = 0; jn < 4; ++jn) acc[i][jn] = (f32x4){0.f, 0.f, 0.f, 0.f};

  // ---- efill (immediate): E[jj&1][c][x] = S[y2][x]-S[y1][x], 3168 f4 tasks
  auto efill_now = [&](int jj) {
    int y1 = (y - jj < 0) ? 0 : (y - jj);
    int y2 = ((y + jj > 127) ? 127 : (y + jj)) + 1;
    float* Ew = E0 + (jj & 1) * EN;
    for (int idx = t; idx < 3168; idx += 1024) {
      int cl = idx / 33;
      int ck = idx - cl * 33;
      const float* bp = Sb + (size_t)cl * 17028 + ck * 4;
      float4 a = *(const float4*)(bp + y2 * 132);
      float4 b = *(const float4*)(bp + y1 * 132);
      float4 d;
      d.x = a.x - b.x; d.y = a.y - b.y; d.z = a.z - b.z; d.w = a.w - b.w;
      *(float4*)(Ew + cl * 132 + ck * 4) = d;
    }
  };

  // ---- build As[jj&1] for ring jj from E[jj&1]: 3072 half-granule tasks
  //      (px, hg of 4 ch), 3 per thread — wave-balanced.
  auto build = [&](int jj) {
    const float* Eb = E0 + (jj & 1) * EN;
    __hip_bfloat16* Ab = A0 + (jj & 1) * AN;
    int x1 = (pxb - jj < 0) ? 0 : (pxb - jj);
    int x2 = ((pxb + jj > 127) ? 127 : (pxb + jj)) + 1;
#pragma unroll
    for (int it = 0; it < 3; ++it) {
      int hg = (t >> 7) + it * 8;            // half-granule 0..23 (4 ch each)
      const float* Er = Eb + hg * 4 * 132;
      union { bf16x4 v; __hip_bfloat16 h[4]; } pk;
#pragma unroll
      for (int i = 0; i < 4; ++i)
        pk.h[i] = __float2bfloat16(Er[i * 132 + x2] - Er[i * 132 + x1]);
      *(bf16x4*)(Ab + pxb * 104 + hg * 4) = pk.v;
    }
  };

  // ---- prologue ----
  efill_now(0);
  __syncthreads();
  build(0);
  efill_now(1);
  __syncthreads();

  // ---- main pipelined ring loop: ONE barrier per ring ----
  for (int j = 0; j < 13; ++j) {
    // (a) issue efill(j+2) loads into registers (longest latency first)
    float4 ea[4], eb[4];
    int e_y1 = 0, e_y2 = 0;
    bool do_e = (j < 11);
    if (do_e) {
      int jj = j + 2;
      e_y1 = (y - jj < 0) ? 0 : (y - jj);
      e_y2 = ((y + jj > 127) ? 127 : (y + jj)) + 1;
#pragma unroll
      for (int it = 0; it < 3; ++it) {
        int idx = t + it * 1024;
        int cl = idx / 33, ck = idx - cl * 33;
        const float* bp = Sb + (size_t)cl * 17028 + ck * 4;
        ea[it] = *(const float4*)(bp + e_y2 * 132);
        eb[it] = *(const float4*)(bp + e_y1 * 132);
      }
      if (t < 96) {
        int idx = t + 3072;
        int cl = idx / 33, ck = idx - cl * 33;
        const float* bp = Sb + (size_t)cl * 17028 + ck * 4;
        ea[3] = *(const float4*)(bp + e_y2 * 132);
        eb[3] = *(const float4*)(bp + e_y1 * 132);
      }
    }

    // (b) MFMA ring j: prefetch all frags, then 48 MFMA
    {
      const __hip_bfloat16* Aj = A0 + (j & 1) * AN;
      bf16x8 af[12], bfr[12];
#pragma unroll
      for (int s = 0; s < 3; ++s)
#pragma unroll
        for (int i = 0; i < 4; ++i)
          af[s * 4 + i] = *(const bf16x8*)(Aj + (wm * 64 + i * 16 + lr) * 104
                                           + s * 32 + quad * 8);
#pragma unroll
      for (int s = 0; s < 3; ++s)
#pragma unroll
        for (int jn = 0; jn < 4; ++jn)
          bfr[s * 4 + jn] = *(const bf16x8*)(V + (size_t)(wn * 64 + jn * 16 + lr) * 1248
                                             + j * 96 + s * 32 + quad * 8);
#pragma unroll
      for (int s = 0; s < 3; ++s)
#pragma unroll
        for (int i = 0; i < 4; ++i)
#pragma unroll
          for (int jn = 0; jn < 4; ++jn)
            acc[i][jn] = __builtin_amdgcn_mfma_f32_16x16x32_bf16(
                af[s * 4 + i], bfr[s * 4 + jn], acc[i][jn], 0, 0, 0);
    }

    // (c) build next ring's As
    if (j < 12) build(j + 1);

    // (d) commit efill(j+2) into E[j&1] (dead buffer)
    if (do_e) {
      float* Ew = E0 + (j & 1) * EN;
#pragma unroll
      for (int it = 0; it < 3; ++it) {
        int idx = t + it * 1024;
        int cl = idx / 33, ck = idx - cl * 33;
        float4 d;
        d.x = ea[it].x - eb[it].x; d.y = ea[it].y - eb[it].y;
        d.z = ea[it].z - eb[it].z; d.w = ea[it].w - eb[it].w;
        *(float4*)(Ew + cl * 132 + ck * 4) = d;
      }
      if (t < 96) {
        int idx = t + 3072;
        int cl = idx / 33, ck = idx - cl * 33;
        float4 d;
        d.x = ea[3].x - eb[3].x; d.y = ea[3].y - eb[3].y;
        d.z = ea[3].z - eb[3].z; d.w = ea[3].w - eb[3].w;
        *(float4*)(Ew + cl * 132 + ck * 4) = d;
      }
    }

    __syncthreads();
  }

  // ---- epilogue A: bias+relu -> Yst[128][520] bf16 (row stride 260 dwords
  //      == 4 mod 32 -> conflict-free b128 reads below) ----
  __hip_bfloat16* Yst = (__hip_bfloat16*)smem;   // 133120 B <= 154624
#pragma unroll
  for (int jn = 0; jn < 4; ++jn) {
    int n = wn * 64 + jn * 16 + lr;
    float bias = b1e[n];
#pragma unroll
    for (int i = 0; i < 4; ++i) {
#pragma unroll
      for (int rr = 0; rr < 4; ++rr) {
        int m = wm * 64 + i * 16 + quad * 4 + rr;
        float z = acc[i][jn][rr] + bias;
        z = z > 0.f ? z : 0.f;
        Yst[m * 520 + n] = __float2bfloat16(z);
      }
    }
  }
  __syncthreads();

  // ---- epilogue B: out[96][128px] = W2e[96][512] x Yst^T ----
  int pxt = wv & 7;          // px tile
  int mh = wv >> 3;          // 0: o2 0..47, 1: o2 48..95
  f32x4 acc2[3];
#pragma unroll
  for (int im = 0; im < 3; ++im) acc2[im] = (f32x4){0.f, 0.f, 0.f, 0.f};

  for (int k2 = 0; k2 < 512; k2 += 32) {
    bf16x8 bfr2 = *(const bf16x8*)(Yst + (pxt * 16 + lr) * 520 + k2 + quad * 8);
#pragma unroll
    for (int im = 0; im < 3; ++im) {
      bf16x8 afr2 = *(const bf16x8*)(W2e + (size_t)(mh * 48 + im * 16 + lr) * 512
                                     + k2 + quad * 8);
      acc2[im] = __builtin_amdgcn_mfma_f32_16x16x32_bf16(afr2, bfr2, acc2[im], 0, 0, 0);
    }
  }

  size_t obase = ((size_t)(b0 + bL) * 96) * 16384 + (size_t)y * 128 + pxt * 16 + lr;
#pragma unroll
  for (int im = 0; im < 3; ++im) {
#pragma unroll
    for (int rr = 0; rr < 4; ++rr) {
      int o2 = mh * 48 + im * 16 + quad * 4 + rr;
      out[obase + (size_t)o2 * 16384] = acc2[im][rr] + b2e[o2];
    }
  }
}

// ---------------------------------------------------------------------------
extern "C" void kernel_launch(void* const* d_in, const int* in_sizes, int n_in,
                              void* d_out, int out_size, void* d_ws, size_t ws_size,
                              hipStream_t stream)
{
  const float* x   = (const float*)d_in[0];
  const float* g1  = (const float*)d_in[1];
  const float* be1 = (const float*)d_in[2];
  const float* mu1 = (const float*)d_in[3];
  const float* va1 = (const float*)d_in[4];
  const float* W1  = (const float*)d_in[5];
  const float* cb1 = (const float*)d_in[6];
  const float* g2  = (const float*)d_in[7];
  const float* be2 = (const float*)d_in[8];
  const float* mu2 = (const float*)d_in[9];
  const float* va2 = (const float*)d_in[10];
  const float* W2  = (const float*)d_in[11];
  const float* cb2 = (const float*)d_in[12];
  float* out = (float*)d_out;

  hipFuncSetAttribute((const void*)fused1_kernel,
                      hipFuncAttributeMaxDynamicSharedMemorySize, 154624);

  char* w = (char*)d_ws;
  __hip_bfloat16* V   = (__hip_bfloat16*)w; w += (size_t)512 * 1248 * 2;
  __hip_bfloat16* W2e = (__hip_bfloat16*)w; w += (size_t)96 * 512 * 2;
  float* b1e = (float*)w; w += 2048;
  float* b2e = (float*)w; w += 512;
  size_t fixed = (size_t)(w - (char*)d_ws);

  const size_t satB = (size_t)96 * 17028 * 4;     // per-batch SAT bytes
  int nb = (ws_size >= fixed + 4 * satB + 4096) ? 4 : 1;

  float* SAT = (float*)w;

  prep1_kernel<<<512, 256, 0, stream>>>(W1, cb1, g1, be1, mu1, va1, V, b1e);
  prep2_kernel<<<96, 256, 0, stream>>>(W2, cb2, g2, be2, mu2, va2, W2e, b2e);

  for (int b0 = 0; b0 < 4; b0 += nb) {
    sat_kernel<<<nb * 96, 128, 0, stream>>>(x + (size_t)b0 * 96 * 16384, SAT);
    fused1_kernel<<<nb * 128, 1024, 154624, stream>>>(SAT, V, b1e, W2e, b2e, out, nb, b0);
  }
}